// Round 13
// baseline (1191.311 us; speedup 1.0000x reference)
//
#include <hip/hip_runtime.h>
#include <hip/hip_bf16.h>

#define N_    20000
#define S_    20
#define NC_   400000
#define EC_   2000000
#define EB_   200000
#define NIN_  64
#define HOP_  16
#define D_    80
#define NOUT_ 64
#define NB_   1563   // ceil(NC/256)
#define NBN_  79     // ceil(N/256)
#define DBIN_ 64     // degree bins for balanced ordering
#define NHB_  391    // ceil(64*NB/256)

typedef __attribute__((ext_vector_type(8))) short bf16x8;
typedef __attribute__((ext_vector_type(4))) float f32x4;
union FragU { uint4 u; bf16x8 b; };

// ---------------- bf16 pack/unpack (pair layout: lo=feat 2p, hi=feat 2p+1) ----------------
__device__ __forceinline__ float2 bf2f(unsigned u) {
    float2 r;
    r.x = __uint_as_float(u << 16);
    r.y = __uint_as_float(u & 0xffff0000u);
    return r;
}
__device__ __forceinline__ unsigned f2bf_rne(float f) {
    unsigned u = __float_as_uint(f);
    return (u + 0x7fffu + ((u >> 16) & 1u)) >> 16;
}
__device__ __forceinline__ unsigned pack2(float a, float b) {
    return f2bf_rne(a) | (f2bf_rne(b) << 16);
}

// accumulate relu(h+ea) for 4 bf16-pairs into A[0..7]
__device__ __forceinline__ void acc4(float* A, uint4 hv, uint4 ev) {
    const unsigned* hp = (const unsigned*)&hv;
    const unsigned* ep = (const unsigned*)&ev;
    #pragma unroll
    for (int j = 0; j < 4; j++) {
        float2 hs = bf2f(hp[j]);
        float2 eq = bf2f(ep[j]);
        A[2 * j]     += fmaxf(hs.x + eq.x, 0.f);
        A[2 * j + 1] += fmaxf(hs.y + eq.y, 0.f);
    }
}
__device__ __forceinline__ void acc4f(float* A, uint4 hv, const float* er, int off) {
    const unsigned* hp = (const unsigned*)&hv;
    #pragma unroll
    for (int j = 0; j < 4; j++) {
        float2 hs = bf2f(hp[j]);
        float2 eq = *(const float2*)(er + 2 * (off + j));
        A[2 * j]     += fmaxf(hs.x + eq.x, 0.f);
        A[2 * j + 1] += fmaxf(hs.y + eq.y, 0.f);
    }
}

// ---------------- scan utility (block of 256 = 4 waves) ----------------
__device__ __forceinline__ int blockExclScan(int v, int tid, int* lds, int* total) {
    int lane = tid & 63;
    int w = tid >> 6;
    int x = v;
    #pragma unroll
    for (int off = 1; off < 64; off <<= 1) {
        int y = __shfl_up(x, off, 64);
        if (lane >= off) x += y;
    }
    if (lane == 63) lds[w] = x;
    __syncthreads();
    if (tid == 0) {
        int acc = 0;
        #pragma unroll
        for (int i = 0; i < 4; i++) { int t = lds[i]; lds[4 + i] = acc; acc += t; }
        lds[8] = acc;
    }
    __syncthreads();
    int res = x - v + lds[4 + w];
    *total = lds[8];
    return res;
}

// ---------------- fused preprocessing: ea16 + xb + htb + gates ----------------
__global__ __launch_bounds__(256) void k_prep(
    unsigned* __restrict__ eab, const float* __restrict__ ea,
    unsigned* __restrict__ xb, const float* __restrict__ x,
    unsigned* __restrict__ htb, const float* __restrict__ ht,
    float* __restrict__ gall,
    const float* __restrict__ gc_w, const float* __restrict__ gc_b,
    const float* __restrict__ gs_w, const float* __restrict__ gs_b,
    const float* __restrict__ gx_w, const float* __restrict__ gx_b)
{
    int idx = blockIdx.x * 256 + threadIdx.x;
    const int R_EA = EB_ * 40;
    const int R_XB = N_ * 32;
    if (idx < R_EA) {
        if (eab) {
            int row = idx / 40, t = idx - row * 40;
            float2 v = *(const float2*)(ea + (size_t)row * 80 + 2 * t);
            eab[idx] = pack2(v.x, v.y);
        }
        return;
    }
    idx -= R_EA;
    if (idx < R_XB) {
        int row = idx >> 5, p = idx & 31;
        float2 v = *(const float2*)(x + (size_t)row * 64 + 2 * p);
        xb[idx] = pack2(v.x, v.y);
        return;
    }
    idx -= R_XB;
    if (idx < 160) {
        int row = idx >> 3, p = idx & 7;
        float2 v = *(const float2*)(ht + (size_t)row * 16 + 2 * p);
        htb[idx] = pack2(v.x, v.y);
        return;
    }
    idx -= 160;
    if (idx < 1280) {
        int h = idx >> 6, d = idx & 63;
        const float* htr = ht + h * 16;
        float a = gc_b[d], b = gs_b[d], c = gx_b[d];
        #pragma unroll
        for (int k = 0; k < 16; k++) {
            float hk = htr[k];
            a += hk * gc_w[k * 64 + d];
            b += hk * gs_w[k * 64 + d];
            c += hk * gx_w[k * 64 + d];
        }
        gall[h * 64 + d]        = 1.f / (1.f + __expf(-a));
        gall[(20 + h) * 64 + d] = 1.f / (1.f + __expf(-b));
        gall[(40 + h) * 64 + d] = 1.f / (1.f + __expf(-c));
    }
}

// ---------------- counts: edge degree + mapper histogram (one pass) ----------------
__global__ __launch_bounds__(256) void k_cnt(
    const int* __restrict__ eidx, int* __restrict__ deg,
    const int* __restrict__ mapper, int* __restrict__ cntm)
{
    int i = blockIdx.x * 256 + threadIdx.x;
    if (i < EC_) atomicAdd(&deg[eidx[EC_ + i]], 1);
    if (i < NC_) atomicAdd(&cntm[mapper[i]], 1);
}

__global__ __launch_bounds__(256) void k_bsum(const int* __restrict__ deg, int* __restrict__ bsums, int n) {
    __shared__ int lds[9];
    int i = blockIdx.x * 256 + threadIdx.x;
    int v = (i < n) ? deg[i] : 0;
    int tot;
    blockExclScan(v, threadIdx.x, lds, &tot);
    if (threadIdx.x == 0) bsums[blockIdx.x] = tot;
}

__global__ __launch_bounds__(256) void k_scan_bsums(int* __restrict__ bsums, int nb) {
    __shared__ int lds[9];
    int carry = 0;
    for (int base = 0; base < nb; base += 256) {
        int i = base + threadIdx.x;
        int v = (i < nb) ? bsums[i] : 0;
        int tot;
        int ex = blockExclScan(v, threadIdx.x, lds, &tot);
        if (i < nb) bsums[i] = ex + carry;
        carry += tot;
        __syncthreads();
    }
}

__global__ __launch_bounds__(256) void k_scan_apply(
    int* __restrict__ cursor, int* __restrict__ start, const int* __restrict__ bsums,
    int n, int total)
{
    __shared__ int lds[9];
    int i = blockIdx.x * 256 + threadIdx.x;
    int v = (i < n) ? cursor[i] : 0;
    int tot;
    int ex = blockExclScan(v, threadIdx.x, lds, &tot);
    if (i < n) {
        int s = ex + bsums[blockIdx.x];
        start[i] = s;
        cursor[i] = s;
    }
    if (blockIdx.x == 0 && threadIdx.x == 0) start[n] = total;
}

// ---------------- fills: e1 (L1: {mapper[src],pk}) + e2 (L2: {src,pk}) + nidx ----------------
__global__ __launch_bounds__(256) void k_fillall(
    const int* __restrict__ eidx, const int* __restrict__ emap,
    const int* __restrict__ hop,
    int* __restrict__ cursor, int2* __restrict__ e1, int2* __restrict__ e2,
    const int* __restrict__ mapper, int* __restrict__ cursor_n, int* __restrict__ nidx)
{
    int i = blockIdx.x * 256 + threadIdx.x;
    if (i < EC_) {
        int src = eidx[i];
        int dst = eidx[EC_ + i];
        int pk = emap[i] * 32 + (hop[src] + 1);
        int pos = atomicAdd(&cursor[dst], 1);
        e2[pos] = make_int2(src, pk);
        e1[pos] = make_int2(mapper[src], pk);
    }
    if (i < NC_) {
        int pos = atomicAdd(&cursor_n[mapper[i]], 1);
        nidx[pos] = i;
    }
}

// ---------------- degree-balanced node order: atomic-free stable counting sort ----------------
__global__ __launch_bounds__(256) void k_lhist(const int* __restrict__ start, int* __restrict__ hist) {
    __shared__ int lh[DBIN_];
    int tid = threadIdx.x;
    if (tid < DBIN_) lh[tid] = 0;
    __syncthreads();
    int i = blockIdx.x * 256 + tid;
    if (i < NC_) {
        int d = min(start[i + 1] - start[i], DBIN_ - 1);
        atomicAdd(&lh[DBIN_ - 1 - d], 1);        // LDS atomic, descending key
    }
    __syncthreads();
    if (tid < DBIN_) hist[tid * NB_ + blockIdx.x] = lh[tid];
}
__global__ __launch_bounds__(256) void k_dscatter2(
    const int* __restrict__ start, const int* __restrict__ hist, int* __restrict__ porder)
{
    __shared__ int lbase[DBIN_];
    int tid = threadIdx.x;
    if (tid < DBIN_) lbase[tid] = hist[tid * NB_ + blockIdx.x];
    __syncthreads();
    int i = blockIdx.x * 256 + tid;
    if (i >= NC_) return;
    int d = min(start[i + 1] - start[i], DBIN_ - 1);
    int pos = atomicAdd(&lbase[DBIN_ - 1 - d], 1);   // LDS atomic, block-local
    porder[pos] = i;
}

// ---------------- fused GINE layer: 4-deep edge-agg + MFMA + epilogue ----------------
// block = 256 = 4 waves; wave owns 16 equal-degree nodes via porder (c = lane&15);
// q = lane>>4 owns K-slices {4q, 16+4q, 32+4q(q<2)} (bf16 pairs). grid = NC/64.
// 4 edges per iteration -> 2x in-flight gathers vs round-11.
template<int L, bool EA16>
__global__ __launch_bounds__(256) void k_gine_f(
    const unsigned* __restrict__ hin,
    const unsigned* __restrict__ xb, const unsigned* __restrict__ htb,
    const int* __restrict__ mapper, const int* __restrict__ hop,
    const unsigned* __restrict__ eab, const float* __restrict__ eaf,
    const int* __restrict__ start, const int2* __restrict__ edesc,
    const int* __restrict__ porder,
    unsigned* __restrict__ outp,
    const float* __restrict__ W, const float* __restrict__ gv, const float* __restrict__ bv)
{
    __shared__ unsigned sWB[5 * 16 * 49];    // 15.7 KB, B-frags, pair-along-k, stride 49
    int tid = threadIdx.x;
    for (int i = tid; i < 5 * 16 * 49; i += 256) {
        int t = i / 784, r2 = i % 784, cc = r2 / 49, kp = r2 % 49;
        int col = 16 * t + cc;
        sWB[i] = (kp < 40) ? pack2(W[(2 * kp) * D_ + col], W[(2 * kp + 1) * D_ + col]) : 0u;
    }
    __syncthreads();

    int w = tid >> 6;
    int lane = tid & 63;
    int q = lane >> 4;
    int c = lane & 15;
    int base = (blockIdx.x * 4 + w) * 16;
    int node = porder[base + c];
    int off0 = 4 * q, off1 = 16 + 4 * q, off2 = 32 + 4 * q;

    // ---- edge aggregation into f32 A-slices (4-deep batch) ----
    float A0[8] = {0.f, 0.f, 0.f, 0.f, 0.f, 0.f, 0.f, 0.f};
    float A1[8] = {0.f, 0.f, 0.f, 0.f, 0.f, 0.f, 0.f, 0.f};
    float A2[8] = {0.f, 0.f, 0.f, 0.f, 0.f, 0.f, 0.f, 0.f};
    uint4 zz = make_uint4(0u, 0u, 0u, 0u);

    int e = start[node];
    int s1 = start[node + 1];
    while (__any(e < s1)) {
        int2 ed[4];
        #pragma unroll
        for (int jj = 0; jj < 4; jj++) {
            int ee = max(min(e + jj, s1 - 1), 0);
            ed[jj] = edesc[ee];
        }
        uint4 hs[4][3];
        #pragma unroll
        for (int jj = 0; jj < 4; jj++) {
            if (L == 1) {
                const unsigned* xr = xb + (size_t)ed[jj].x * 32;   // ed.x == mapper[src]
                hs[jj][0] = *(const uint4*)(xr + off0);
                hs[jj][1] = *(const uint4*)(xr + off1);
                hs[jj][2] = (q < 2) ? *(const uint4*)(htb + (ed[jj].y & 31) * 8 + off0) : zz;
            } else {
                const unsigned* hr = hin + (size_t)ed[jj].x * 40;
                hs[jj][0] = *(const uint4*)(hr + off0);
                hs[jj][1] = *(const uint4*)(hr + off1);
                hs[jj][2] = (q < 2) ? *(const uint4*)(hr + off2) : zz;
            }
        }
        if (EA16) {
            uint4 es[4][3];
            #pragma unroll
            for (int jj = 0; jj < 4; jj++) {
                const unsigned* ep = eab + (size_t)(ed[jj].y >> 5) * 40;
                es[jj][0] = *(const uint4*)(ep + off0);
                es[jj][1] = *(const uint4*)(ep + off1);
                es[jj][2] = (q < 2) ? *(const uint4*)(ep + off2) : zz;
            }
            #pragma unroll
            for (int jj = 0; jj < 4; jj++) {
                if (e + jj < s1) {
                    acc4(A0, hs[jj][0], es[jj][0]);
                    acc4(A1, hs[jj][1], es[jj][1]);
                    if (q < 2) acc4(A2, hs[jj][2], es[jj][2]);
                }
            }
        } else {
            #pragma unroll
            for (int jj = 0; jj < 4; jj++) {
                const float* ep = eaf + (size_t)(ed[jj].y >> 5) * 80;
                if (e + jj < s1) {
                    acc4f(A0, hs[jj][0], ep, off0);
                    acc4f(A1, hs[jj][1], ep, off1);
                    if (q < 2) acc4f(A2, hs[jj][2], ep, off2);
                }
            }
        }
        e += 4;
    }

    // ---- own h (A-slices) ----
    uint4 h0v, h1v, h2v;
    if (L == 1) {
        int m = mapper[node];
        int hp = hop[node] + 1;
        const unsigned* xr = xb + (size_t)m * 32;
        h0v = *(const uint4*)(xr + off0);
        h1v = *(const uint4*)(xr + off1);
        h2v = (q < 2) ? *(const uint4*)(htb + hp * 8 + off0) : zz;
    } else {
        const unsigned* hr = hin + (size_t)node * 40;
        h0v = *(const uint4*)(hr + off0);
        h1v = *(const uint4*)(hr + off1);
        h2v = (q < 2) ? *(const uint4*)(hr + off2) : zz;
    }

    // ---- A = bf16(h + agg) ----
    FragU a0F, a1F, a2F;
    {
        const unsigned* hp0 = (const unsigned*)&h0v;
        const unsigned* hp1 = (const unsigned*)&h1v;
        const unsigned* hp2 = (const unsigned*)&h2v;
        unsigned r0[4], r1[4], r2[4];
        #pragma unroll
        for (int j = 0; j < 4; j++) {
            float2 f0 = bf2f(hp0[j]);
            float2 f1 = bf2f(hp1[j]);
            float2 f2 = bf2f(hp2[j]);
            r0[j] = pack2(A0[2 * j] + f0.x, A0[2 * j + 1] + f0.y);
            r1[j] = pack2(A1[2 * j] + f1.x, A1[2 * j + 1] + f1.y);
            r2[j] = (q < 2) ? pack2(A2[2 * j] + f2.x, A2[2 * j + 1] + f2.y) : 0u;
        }
        a0F.u = make_uint4(r0[0], r0[1], r0[2], r0[3]);
        a1F.u = make_uint4(r1[0], r1[1], r1[2], r1[3]);
        a2F.u = make_uint4(r2[0], r2[1], r2[2], r2[3]);
    }

    // ---- GEMM: 5 col-tiles x 3 K-steps = 15 MFMA ----
    f32x4 acc[5];
    #pragma unroll
    for (int t = 0; t < 5; t++) {
        const unsigned* pb = sWB + (t * 16 + c) * 49 + 4 * q;
        FragU b0, b1, b2;
        b0.u = *(const uint4*)(pb);
        b1.u = *(const uint4*)(pb + 16);
        b2.u = *(const uint4*)(pb + 32);
        f32x4 z = {0.f, 0.f, 0.f, 0.f};
        acc[t] = __builtin_amdgcn_mfma_f32_16x16x32_bf16(a0F.b, b0.b, z, 0, 0, 0);
        acc[t] = __builtin_amdgcn_mfma_f32_16x16x32_bf16(a1F.b, b1.b, acc[t], 0, 0, 0);
        acc[t] = __builtin_amdgcn_mfma_f32_16x16x32_bf16(a2F.b, b2.b, acc[t], 0, 0, 0);
    }

    // ---- epilogue rows 4q+r: BN + ReLU + residual, pack-store ----
    int prow[4], mm2[4], hp2v[4];
    #pragma unroll
    for (int r = 0; r < 4; r++) {
        prow[r] = porder[base + 4 * q + r];
        if (L == 1) {
            mm2[r] = mapper[prow[r]];
            hp2v[r] = hop[prow[r]] + 1;
        }
    }
    #pragma unroll
    for (int t = 0; t < 5; t++) {
        int col = 16 * t + c;
        float gc_ = gv[col], bc_ = bv[col];
        #pragma unroll
        for (int r = 0; r < 4; r++) {
            unsigned hu;
            if (L == 1) {
                hu = (t < 4) ? xb[(size_t)mm2[r] * 32 + 8 * t + (c >> 1)]
                             : htb[hp2v[r] * 8 + (c >> 1)];
            } else {
                hu = hin[(size_t)prow[r] * 40 + 8 * t + (c >> 1)];
            }
            float2 hf = bf2f(hu);
            float hres = (c & 1) ? hf.y : hf.x;
            float o = fmaxf(gc_ * acc[t][r] + bc_, 0.f) + hres;
            float partner = __shfl_xor(o, 1);
            if (!(c & 1)) outp[(size_t)prow[r] * 40 + 8 * t + (c >> 1)] = pack2(o, partner);
        }
    }
}

// ---------------- MFMA head: oe + gates + sub/ctx; atomic-light pooling ----------------
__global__ __launch_bounds__(256) void k_headm(
    const unsigned* __restrict__ h2u, const int* __restrict__ hop,
    const int* __restrict__ mapper, const float* __restrict__ gall,
    const float* __restrict__ oe_w, const float* __restrict__ oe_b,
    const float* __restrict__ sub_w, const float* __restrict__ sub_b,
    const float* __restrict__ sub_g, const float* __restrict__ sub_bt,
    const float* __restrict__ ctx_w, const float* __restrict__ ctx_b,
    const float* __restrict__ ctx_g, const float* __restrict__ ctx_bt,
    float* __restrict__ cent, float* __restrict__ subp, unsigned* __restrict__ ctxv)
{
    __shared__ unsigned sOE[4 * 16 * 48];   // 12 KB
    __shared__ unsigned sSB[4 * 16 * 40];   // 10 KB
    __shared__ unsigned sCX[4 * 16 * 40];   // 10 KB
    __shared__ float    sT[4][16 * 68];     // 17 KB
    int tid = threadIdx.x;
    for (int i = tid; i < 4 * 16 * 48; i += 256) {
        int t = i / (16 * 48), r2 = i % (16 * 48), cc = r2 / 48, kp = r2 % 48;
        int col = 16 * t + cc;
        sOE[i] = (kp < 40) ? pack2(oe_w[(2 * kp) * 64 + col], oe_w[(2 * kp + 1) * 64 + col]) : 0u;
    }
    for (int i = tid; i < 4 * 16 * 40; i += 256) {
        int t = i / (16 * 40), r2 = i % (16 * 40), cc = r2 / 40, kp = r2 % 40;
        int col = 16 * t + cc;
        bool ok = kp < 32;
        sSB[i] = ok ? pack2(sub_w[(2 * kp) * 64 + col], sub_w[(2 * kp + 1) * 64 + col]) : 0u;
        sCX[i] = ok ? pack2(ctx_w[(2 * kp) * 64 + col], ctx_w[(2 * kp + 1) * 64 + col]) : 0u;
    }
    __syncthreads();

    int w = tid >> 6;
    int lane = tid & 63;
    int q = lane >> 4;
    int c = lane & 15;
    int base = (blockIdx.x * 4 + w) * 16;

    const uint4* hrow = (const uint4*)(h2u + (size_t)(base + c) * 40);
    FragU a0, a1, a2;
    a0.u = hrow[q];
    a1.u = hrow[4 + q];
    a2.u = make_uint4(0u, 0u, 0u, 0u);
    if (q < 2) a2.u = hrow[8 + q];

    f32x4 acc[4];
    #pragma unroll
    for (int t = 0; t < 4; t++) {
        const unsigned* pb = sOE + (t * 16 + c) * 48 + 4 * q;
        FragU b0, b1, b2;
        b0.u = *(const uint4*)(pb);
        b1.u = *(const uint4*)(pb + 16);
        b2.u = *(const uint4*)(pb + 32);
        f32x4 z = {0.f, 0.f, 0.f, 0.f};
        acc[t] = __builtin_amdgcn_mfma_f32_16x16x32_bf16(a0.b, b0.b, z, 0, 0, 0);
        acc[t] = __builtin_amdgcn_mfma_f32_16x16x32_bf16(a1.b, b1.b, acc[t], 0, 0, 0);
        acc[t] = __builtin_amdgcn_mfma_f32_16x16x32_bf16(a2.b, b2.b, acc[t], 0, 0, 0);
    }

    int mm[4], hn[4];
    #pragma unroll
    for (int r = 0; r < 4; r++) {
        int node = base + 4 * q + r;
        mm[r] = mapper[node];
        hn[r] = hop[node] + 1;
    }
    int sgA = base / S_;
    int k0 = (sgA + 1) * S_ - base;
    if (k0 > 16) k0 = 16;

    #pragma unroll
    for (int t = 0; t < 4; t++) {
        int col = 16 * t + c;
        float ob = oe_b[col];
        #pragma unroll
        for (int r = 0; r < 4; r++) {
            int row = 4 * q + r;
            float v = acc[t][r] + ob;
            sT[w][row * 68 + col] = v;
            int sg = (row < k0) ? sgA : sgA + 1;
            if (mm[r] == sg) {
                cent[(size_t)sg * 64 + col] = v * gall[hn[r] * 64 + col];
            }
        }
    }

    const float* trp = &sT[w][c * 68 + 8 * q];
    float4 v0 = *(const float4*)(trp);
    float4 v1 = *(const float4*)(trp + 4);
    float4 v2 = *(const float4*)(trp + 32);
    float4 v3 = *(const float4*)(trp + 36);
    FragU ap0, ap1;
    ap0.u = make_uint4(pack2(v0.x, v0.y), pack2(v0.z, v0.w), pack2(v1.x, v1.y), pack2(v1.z, v1.w));
    ap1.u = make_uint4(pack2(v2.x, v2.y), pack2(v2.z, v2.w), pack2(v3.x, v3.y), pack2(v3.z, v3.w));

    f32x4 sa[4], ca[4];
    #pragma unroll
    for (int t = 0; t < 4; t++) {
        const unsigned* ps = sSB + (t * 16 + c) * 40 + 4 * q;
        const unsigned* pc = sCX + (t * 16 + c) * 40 + 4 * q;
        FragU b0, b1, d0, d1;
        b0.u = *(const uint4*)(ps);
        b1.u = *(const uint4*)(ps + 16);
        d0.u = *(const uint4*)(pc);
        d1.u = *(const uint4*)(pc + 16);
        f32x4 z = {0.f, 0.f, 0.f, 0.f};
        sa[t] = __builtin_amdgcn_mfma_f32_16x16x32_bf16(ap0.b, b0.b, z, 0, 0, 0);
        sa[t] = __builtin_amdgcn_mfma_f32_16x16x32_bf16(ap1.b, b1.b, sa[t], 0, 0, 0);
        ca[t] = __builtin_amdgcn_mfma_f32_16x16x32_bf16(ap0.b, d0.b, z, 0, 0, 0);
        ca[t] = __builtin_amdgcn_mfma_f32_16x16x32_bf16(ap1.b, d1.b, ca[t], 0, 0, 0);
    }

    #pragma unroll
    for (int t = 0; t < 4; t++) {
        int col = 16 * t + c;
        float sb = sub_b[col], sgm = sub_g[col], sbt = sub_bt[col];
        float cb = ctx_b[col], cgm = ctx_g[col], cbt = ctx_bt[col];
        float sA = 0.f, sB = 0.f;
        #pragma unroll
        for (int r = 0; r < 4; r++) {
            int row = 4 * q + r;
            float sval = fmaxf(sgm * (sa[t][r] + sb) + sbt, 0.f) * gall[(20 + hn[r]) * 64 + col];
            float cval = fmaxf(cgm * (ca[t][r] + cb) + cbt, 0.f) * gall[(40 + hn[r]) * 64 + col];
            float partner = __shfl_xor(cval, 1);
            if ((c & 1) == 0) {
                ctxv[(size_t)(base + row) * 32 + (col >> 1)] = pack2(cval, partner);
            }
            if (row < k0) sA += sval; else sB += sval;
        }
        sA += __shfl_xor(sA, 16); sA += __shfl_xor(sA, 32);
        sB += __shfl_xor(sB, 16); sB += __shfl_xor(sB, 32);
        if (q == 0) {
            atomicAdd(&subp[(size_t)sgA * 64 + col], sA);
            if (k0 < 16) atomicAdd(&subp[(size_t)(sgA + 1) * 64 + col], sB);
        }
    }
}

// ---------------- ctx pool: gather ctxv rows by node-CSR (4-batched) ----------------
__global__ __launch_bounds__(256) void k_ctxpool(
    const unsigned* __restrict__ ctxv, const int* __restrict__ nstart,
    const int* __restrict__ nidx, float* __restrict__ ctxp)
{
    int w = threadIdx.x >> 6, d = threadIdx.x & 63;
    int n = blockIdx.x * 4 + w;
    if (n >= N_) return;
    int s0 = nstart[n], s1 = nstart[n + 1];
    int dh = d >> 1;
    float acc = 0.f;
    int i = s0;
    for (; i + 4 <= s1; i += 4) {
        int r0 = nidx[i], r1 = nidx[i + 1], r2 = nidx[i + 2], r3 = nidx[i + 3];
        float2 f0 = bf2f(ctxv[(size_t)r0 * 32 + dh]);
        float2 f1 = bf2f(ctxv[(size_t)r1 * 32 + dh]);
        float2 f2 = bf2f(ctxv[(size_t)r2 * 32 + dh]);
        float2 f3 = bf2f(ctxv[(size_t)r3 * 32 + dh]);
        acc += (d & 1) ? (f0.y + f1.y + f2.y + f3.y) : (f0.x + f1.x + f2.x + f3.x);
    }
    for (; i < s1; i++) {
        float2 f = bf2f(ctxv[(size_t)nidx[i] * 32 + dh]);
        acc += (d & 1) ? f.y : f.x;
    }
    ctxp[(size_t)n * 64 + d] = acc;
}

// ---------------- final: combine pools + out_encoder ----------------
__global__ __launch_bounds__(256) void k_final(
    const float* __restrict__ cent, const float* __restrict__ subp, const float* __restrict__ ctxp,
    const int* __restrict__ nstart,
    const float* __restrict__ fo_w, const float* __restrict__ fo_b,
    const float* __restrict__ fo_g, const float* __restrict__ fo_bt,
    float* __restrict__ out)
{
    __shared__ float sW[64 * 64];
    int tid = threadIdx.x;
    for (int i = tid; i < 4096; i += 256) sW[i] = fo_w[i];
    int d = tid & 63, grp = tid >> 6;
    float rb = fo_b[d], rg = fo_g[d], rbt = fo_bt[d];
    __syncthreads();
    for (int n = blockIdx.x * 4 + grp; n < N_; n += gridDim.x * 4) {
        float cm = (float)max(nstart[n + 1] - nstart[n], 1);
        size_t o = (size_t)n * 64 + d;
        float r = cent[o] + subp[o] * (1.f / 20.f) + ctxp[o] / cm;
        float dot = rb;
        #pragma unroll 8
        for (int k = 0; k < 64; k++) dot += __shfl(r, k) * sW[k * 64 + d];
        out[o] = rg * dot + rbt;
    }
}

// ---------------- launch ----------------
extern "C" void kernel_launch(void* const* d_in, const int* in_sizes, int n_in,
                              void* d_out, int out_size, void* d_ws, size_t ws_size,
                              hipStream_t stream) {
    const float* x         = (const float*)d_in[0];
    const float* edge_attr = (const float*)d_in[1];
    const float* hop_table = (const float*)d_in[2];
    const float* conv_w1   = (const float*)d_in[3];
    const float* bn1_g     = (const float*)d_in[4];
    const float* bn1_b     = (const float*)d_in[5];
    const float* conv_w2   = (const float*)d_in[6];
    const float* bn2_g     = (const float*)d_in[7];
    const float* bn2_b     = (const float*)d_in[8];
    const float* oe_w      = (const float*)d_in[9];
    const float* oe_b      = (const float*)d_in[10];
    const float* sub_w     = (const float*)d_in[11];
    const float* sub_b     = (const float*)d_in[12];
    const float* sub_g     = (const float*)d_in[13];
    const float* sub_bt    = (const float*)d_in[14];
    const float* ctx_w     = (const float*)d_in[15];
    const float* ctx_b     = (const float*)d_in[16];
    const float* ctx_g     = (const float*)d_in[17];
    const float* ctx_bt    = (const float*)d_in[18];
    const float* gc_w      = (const float*)d_in[19];
    const float* gc_b      = (const float*)d_in[20];
    const float* gs_w      = (const float*)d_in[21];
    const float* gs_b      = (const float*)d_in[22];
    const float* gx_w      = (const float*)d_in[23];
    const float* gx_b      = (const float*)d_in[24];
    const float* fo_w      = (const float*)d_in[25];
    const float* fo_b      = (const float*)d_in[26];
    const float* fo_g      = (const float*)d_in[27];
    const float* fo_bt     = (const float*)d_in[28];
    const int* nodes_mapper  = (const int*)d_in[29];
    const int* edges_mapper  = (const int*)d_in[30];
    const int* edge_index    = (const int*)d_in[31];
    const int* batch         = (const int*)d_in[32];
    const int* hop_indicator = (const int*)d_in[33];
    (void)batch;
    float* out = (float*)d_out;

    size_t off = 0;
    auto alloc = [&](size_t bytes) -> char* {
        char* p = (char*)d_ws + off;
        off = (off + bytes + 255) & ~(size_t)255;
        return p;
    };
    unsigned* hbuf0 = (unsigned*)alloc((size_t)NC_ * 40 * 4);  // 64 MB: h2
    unsigned* hbuf1 = (unsigned*)alloc((size_t)NC_ * 40 * 4);  // 64 MB: h1 -> ctxv
    int*   start    = (int*)alloc((size_t)(NC_ + 1) * 4);
    int*   cursor   = (int*)alloc((size_t)NC_ * 4);
    int*   bsums    = (int*)alloc(2048 * 4);
    int2*  e1       = (int2*)alloc((size_t)EC_ * 8);           // 16 MB (L1: {mapper[src],pk})
    int2*  e2       = (int2*)alloc((size_t)EC_ * 8);           // 16 MB (L2: {src,pk})
    float* cent     = (float*)alloc((size_t)N_ * 64 * 4);
    float* subp     = (float*)alloc((size_t)N_ * 64 * 4);
    float* ctxp     = (float*)alloc((size_t)N_ * 64 * 4);
    int*   nstart   = (int*)alloc((size_t)(N_ + 1) * 4);
    int*   cursor_n = (int*)alloc((size_t)N_ * 4);
    int*   bsums_n  = (int*)alloc(256 * 4);
    int*   nidx     = (int*)alloc((size_t)NC_ * 4);
    float* gall     = (float*)alloc((size_t)60 * 64 * 4);
    unsigned* xb    = (unsigned*)alloc((size_t)N_ * 32 * 4);   // 2.56 MB
    unsigned* htb   = (unsigned*)alloc((size_t)20 * 8 * 4);
    int*   hist     = (int*)alloc((size_t)(DBIN_ * NB_ + 1) * 4);  // 400 KB
    int*   bsums_h  = (int*)alloc(512 * 4);
    int*   porder   = (int*)alloc((size_t)NC_ * 4);            // 1.6 MB
    size_t ea16_bytes = (size_t)EB_ * 40 * 4;                  // 32 MB
    bool use_ea16 = (off + ea16_bytes + 256) <= ws_size;
    unsigned* eab = use_ea16 ? (unsigned*)alloc(ea16_bytes) : nullptr;
    unsigned* ctxv = hbuf1;
    (void)in_sizes; (void)n_in; (void)out_size;

    hipMemsetAsync(cursor, 0, (size_t)NC_ * 4, stream);
    hipMemsetAsync(cursor_n, 0, (size_t)N_ * 4, stream);
    hipMemsetAsync(subp, 0, (size_t)N_ * 64 * 4, stream);

    // fused preprocessing (ea16 + xb + htb + gates)
    {
        int total = EB_ * 40 + N_ * 32 + 160 + 1280;
        k_prep<<<(total + 255) / 256, 256, 0, stream>>>(eab, edge_attr, xb, x, htb, hop_table,
                                                        gall, gc_w, gc_b, gs_w, gs_b, gx_w, gx_b);
    }

    // counts (edge degree + mapper histogram), then the two scans
    k_cnt<<<(EC_ + 255) / 256, 256, 0, stream>>>(edge_index, cursor, nodes_mapper, cursor_n);
    k_bsum<<<NB_, 256, 0, stream>>>(cursor, bsums, NC_);
    k_scan_bsums<<<1, 256, 0, stream>>>(bsums, NB_);
    k_scan_apply<<<NB_, 256, 0, stream>>>(cursor, start, bsums, NC_, EC_);
    k_bsum<<<NBN_, 256, 0, stream>>>(cursor_n, bsums_n, N_);
    k_scan_bsums<<<1, 256, 0, stream>>>(bsums_n, NBN_);
    k_scan_apply<<<NBN_, 256, 0, stream>>>(cursor_n, nstart, bsums_n, N_, NC_);

    // fills (e1 + e2 + nidx)
    k_fillall<<<(EC_ + 255) / 256, 256, 0, stream>>>(edge_index, edges_mapper, hop_indicator,
                                                     cursor, e1, e2, nodes_mapper, cursor_n, nidx);

    // degree-balanced node order (descending degree; atomic-free counting sort)
    k_lhist<<<NB_, 256, 0, stream>>>(start, hist);
    k_bsum<<<NHB_, 256, 0, stream>>>(hist, bsums_h, DBIN_ * NB_);
    k_scan_bsums<<<1, 256, 0, stream>>>(bsums_h, NHB_);
    k_scan_apply<<<NHB_, 256, 0, stream>>>(hist, hist, bsums_h, DBIN_ * NB_, NC_);
    k_dscatter2<<<NB_, 256, 0, stream>>>(start, hist, porder);

    // fused layers (degree-balanced waves, heavy-first dispatch, 4-deep edge batch)
    if (use_ea16) {
        k_gine_f<1, true><<<NC_ / 64, 256, 0, stream>>>(nullptr, xb, htb, nodes_mapper,
                                                        hop_indicator, eab, edge_attr,
                                                        start, e1, porder, hbuf1,
                                                        conv_w1, bn1_g, bn1_b);
        k_gine_f<2, true><<<NC_ / 64, 256, 0, stream>>>(hbuf1, xb, htb, nodes_mapper,
                                                        hop_indicator, eab, edge_attr,
                                                        start, e2, porder, hbuf0,
                                                        conv_w2, bn2_g, bn2_b);
    } else {
        k_gine_f<1, false><<<NC_ / 64, 256, 0, stream>>>(nullptr, xb, htb, nodes_mapper,
                                                         hop_indicator, eab, edge_attr,
                                                         start, e1, porder, hbuf1,
                                                         conv_w1, bn1_g, bn1_b);
        k_gine_f<2, false><<<NC_ / 64, 256, 0, stream>>>(hbuf1, xb, htb, nodes_mapper,
                                                         hop_indicator, eab, edge_attr,
                                                         start, e2, porder, hbuf0,
                                                         conv_w2, bn2_g, bn2_b);
    }

    // MFMA head (h2 = hbuf0; ctxv aliases hbuf1)
    k_headm<<<NC_ / 64, 256, 0, stream>>>(hbuf0, hop_indicator, nodes_mapper, gall,
                                          oe_w, oe_b, sub_w, sub_b, sub_g, sub_bt,
                                          ctx_w, ctx_b, ctx_g, ctx_bt,
                                          cent, subp, ctxv);

    // ctx pool via node-CSR gather
    k_ctxpool<<<N_ / 4, 256, 0, stream>>>(ctxv, nstart, nidx, ctxp);

    // final combine + out encoder
    k_final<<<1280, 256, 0, stream>>>(cent, subp, ctxp, nstart, fo_w, fo_b, fo_g, fo_bt, out);
}

// Round 14
// 1044.261 us; speedup vs baseline: 1.1408x; 1.1408x over previous
//
#include <hip/hip_runtime.h>
#include <hip/hip_bf16.h>

#define N_    20000
#define S_    20
#define NC_   400000
#define EC_   2000000
#define EB_   200000
#define NIN_  64
#define HOP_  16
#define D_    80
#define NOUT_ 64
#define NB_   1563   // ceil(NC/256)
#define NBN_  79     // ceil(N/256)
#define DBIN_ 64     // degree bins for balanced ordering
#define NHB_  391    // ceil(64*NB/256)

typedef __attribute__((ext_vector_type(8))) short bf16x8;
typedef __attribute__((ext_vector_type(4))) float f32x4;
union FragU { uint4 u; bf16x8 b; };

// ---------------- bf16 pack/unpack (pair layout: lo=feat 2p, hi=feat 2p+1) ----------------
__device__ __forceinline__ float2 bf2f(unsigned u) {
    float2 r;
    r.x = __uint_as_float(u << 16);
    r.y = __uint_as_float(u & 0xffff0000u);
    return r;
}
__device__ __forceinline__ unsigned f2bf_rne(float f) {
    unsigned u = __float_as_uint(f);
    return (u + 0x7fffu + ((u >> 16) & 1u)) >> 16;
}
__device__ __forceinline__ unsigned pack2(float a, float b) {
    return f2bf_rne(a) | (f2bf_rne(b) << 16);
}

// accumulate relu(h+ea) for 4 bf16-pairs into A[0..7]
__device__ __forceinline__ void acc4(float* A, uint4 hv, uint4 ev) {
    const unsigned* hp = (const unsigned*)&hv;
    const unsigned* ep = (const unsigned*)&ev;
    #pragma unroll
    for (int j = 0; j < 4; j++) {
        float2 hs = bf2f(hp[j]);
        float2 eq = bf2f(ep[j]);
        A[2 * j]     += fmaxf(hs.x + eq.x, 0.f);
        A[2 * j + 1] += fmaxf(hs.y + eq.y, 0.f);
    }
}
__device__ __forceinline__ void acc4f(float* A, uint4 hv, const float* er, int off) {
    const unsigned* hp = (const unsigned*)&hv;
    #pragma unroll
    for (int j = 0; j < 4; j++) {
        float2 hs = bf2f(hp[j]);
        float2 eq = *(const float2*)(er + 2 * (off + j));
        A[2 * j]     += fmaxf(hs.x + eq.x, 0.f);
        A[2 * j + 1] += fmaxf(hs.y + eq.y, 0.f);
    }
}

// ---------------- scan utility (block of 256 = 4 waves) ----------------
__device__ __forceinline__ int blockExclScan(int v, int tid, int* lds, int* total) {
    int lane = tid & 63;
    int w = tid >> 6;
    int x = v;
    #pragma unroll
    for (int off = 1; off < 64; off <<= 1) {
        int y = __shfl_up(x, off, 64);
        if (lane >= off) x += y;
    }
    if (lane == 63) lds[w] = x;
    __syncthreads();
    if (tid == 0) {
        int acc = 0;
        #pragma unroll
        for (int i = 0; i < 4; i++) { int t = lds[i]; lds[4 + i] = acc; acc += t; }
        lds[8] = acc;
    }
    __syncthreads();
    int res = x - v + lds[4 + w];
    *total = lds[8];
    return res;
}

// ---------------- fused preprocessing: ea16 + xb + htb + gates ----------------
__global__ __launch_bounds__(256) void k_prep(
    unsigned* __restrict__ eab, const float* __restrict__ ea,
    unsigned* __restrict__ xb, const float* __restrict__ x,
    unsigned* __restrict__ htb, const float* __restrict__ ht,
    float* __restrict__ gall,
    const float* __restrict__ gc_w, const float* __restrict__ gc_b,
    const float* __restrict__ gs_w, const float* __restrict__ gs_b,
    const float* __restrict__ gx_w, const float* __restrict__ gx_b)
{
    int idx = blockIdx.x * 256 + threadIdx.x;
    const int R_EA = EB_ * 40;
    const int R_XB = N_ * 32;
    if (idx < R_EA) {
        if (eab) {
            int row = idx / 40, t = idx - row * 40;
            float2 v = *(const float2*)(ea + (size_t)row * 80 + 2 * t);
            eab[idx] = pack2(v.x, v.y);
        }
        return;
    }
    idx -= R_EA;
    if (idx < R_XB) {
        int row = idx >> 5, p = idx & 31;
        float2 v = *(const float2*)(x + (size_t)row * 64 + 2 * p);
        xb[idx] = pack2(v.x, v.y);
        return;
    }
    idx -= R_XB;
    if (idx < 160) {
        int row = idx >> 3, p = idx & 7;
        float2 v = *(const float2*)(ht + (size_t)row * 16 + 2 * p);
        htb[idx] = pack2(v.x, v.y);
        return;
    }
    idx -= 160;
    if (idx < 1280) {
        int h = idx >> 6, d = idx & 63;
        const float* htr = ht + h * 16;
        float a = gc_b[d], b = gs_b[d], c = gx_b[d];
        #pragma unroll
        for (int k = 0; k < 16; k++) {
            float hk = htr[k];
            a += hk * gc_w[k * 64 + d];
            b += hk * gs_w[k * 64 + d];
            c += hk * gx_w[k * 64 + d];
        }
        gall[h * 64 + d]        = 1.f / (1.f + __expf(-a));
        gall[(20 + h) * 64 + d] = 1.f / (1.f + __expf(-b));
        gall[(40 + h) * 64 + d] = 1.f / (1.f + __expf(-c));
    }
}

// ---------------- counts: edge degree + mapper histogram (one pass) ----------------
__global__ __launch_bounds__(256) void k_cnt(
    const int* __restrict__ eidx, int* __restrict__ deg,
    const int* __restrict__ mapper, int* __restrict__ cntm)
{
    int i = blockIdx.x * 256 + threadIdx.x;
    if (i < EC_) atomicAdd(&deg[eidx[EC_ + i]], 1);
    if (i < NC_) atomicAdd(&cntm[mapper[i]], 1);
}

__global__ __launch_bounds__(256) void k_bsum(const int* __restrict__ deg, int* __restrict__ bsums, int n) {
    __shared__ int lds[9];
    int i = blockIdx.x * 256 + threadIdx.x;
    int v = (i < n) ? deg[i] : 0;
    int tot;
    blockExclScan(v, threadIdx.x, lds, &tot);
    if (threadIdx.x == 0) bsums[blockIdx.x] = tot;
}

__global__ __launch_bounds__(256) void k_scan_bsums(int* __restrict__ bsums, int nb) {
    __shared__ int lds[9];
    int carry = 0;
    for (int base = 0; base < nb; base += 256) {
        int i = base + threadIdx.x;
        int v = (i < nb) ? bsums[i] : 0;
        int tot;
        int ex = blockExclScan(v, threadIdx.x, lds, &tot);
        if (i < nb) bsums[i] = ex + carry;
        carry += tot;
        __syncthreads();
    }
}

__global__ __launch_bounds__(256) void k_scan_apply(
    int* __restrict__ cursor, int* __restrict__ start, const int* __restrict__ bsums,
    int n, int total)
{
    __shared__ int lds[9];
    int i = blockIdx.x * 256 + threadIdx.x;
    int v = (i < n) ? cursor[i] : 0;
    int tot;
    int ex = blockExclScan(v, threadIdx.x, lds, &tot);
    if (i < n) {
        int s = ex + bsums[blockIdx.x];
        start[i] = s;
        cursor[i] = s;
    }
    if (blockIdx.x == 0 && threadIdx.x == 0) start[n] = total;
}

// ---------------- fills: e2 edge records + nidx/npos node records (one pass) ----------------
__global__ __launch_bounds__(256) void k_fillall(
    const int* __restrict__ eidx, const int* __restrict__ emap,
    const int* __restrict__ hop,
    int* __restrict__ cursor, int2* __restrict__ e2,
    const int* __restrict__ mapper, int* __restrict__ cursor_n,
    int* __restrict__ nidx, int* __restrict__ npos)
{
    int i = blockIdx.x * 256 + threadIdx.x;
    if (i < EC_) {
        int src = eidx[i];
        int dst = eidx[EC_ + i];
        int pk = emap[i] * 32 + (hop[src] + 1);
        int pos = atomicAdd(&cursor[dst], 1);
        e2[pos] = make_int2(src, pk);
    }
    if (i < NC_) {
        int pos = atomicAdd(&cursor_n[mapper[i]], 1);
        nidx[pos] = i;
        npos[i] = pos;
    }
}

// ---------------- degree-balanced node order: atomic-free stable counting sort ----------------
// DESCENDING degree (heavy blocks dispatched first -> no scheduling tail).
__global__ __launch_bounds__(256) void k_lhist(const int* __restrict__ start, int* __restrict__ hist) {
    __shared__ int lh[DBIN_];
    int tid = threadIdx.x;
    if (tid < DBIN_) lh[tid] = 0;
    __syncthreads();
    int i = blockIdx.x * 256 + tid;
    if (i < NC_) {
        int d = min(start[i + 1] - start[i], DBIN_ - 1);
        atomicAdd(&lh[DBIN_ - 1 - d], 1);        // LDS atomic, descending key
    }
    __syncthreads();
    if (tid < DBIN_) hist[tid * NB_ + blockIdx.x] = lh[tid];
}
__global__ __launch_bounds__(256) void k_dscatter2(
    const int* __restrict__ start, const int* __restrict__ hist, int* __restrict__ porder)
{
    __shared__ int lbase[DBIN_];
    int tid = threadIdx.x;
    if (tid < DBIN_) lbase[tid] = hist[tid * NB_ + blockIdx.x];
    __syncthreads();
    int i = blockIdx.x * 256 + tid;
    if (i >= NC_) return;
    int d = min(start[i + 1] - start[i], DBIN_ - 1);
    int pos = atomicAdd(&lbase[DBIN_ - 1 - d], 1);   // LDS atomic, block-local
    porder[pos] = i;
}

// ---------------- fused GINE layer: edge-agg in A-fragment layout + MFMA + epilogue ----------------
// block = 256 = 4 waves; wave owns 16 equal-degree nodes via porder (c = lane&15);
// q = lane>>4 owns K-slices {4q, 16+4q, 32+4q(q<2)} (bf16 pairs). grid = NC/64.
// Round-10 best config: 2-edge batch, no descriptor prefetch.
template<int L, bool EA16>
__global__ __launch_bounds__(256) void k_gine_f(
    const unsigned* __restrict__ hin,
    const unsigned* __restrict__ xb, const unsigned* __restrict__ htb,
    const int* __restrict__ mapper, const int* __restrict__ hop,
    const unsigned* __restrict__ eab, const float* __restrict__ eaf,
    const int* __restrict__ start, const int2* __restrict__ e2,
    const int* __restrict__ porder,
    unsigned* __restrict__ outp,
    const float* __restrict__ W, const float* __restrict__ gv, const float* __restrict__ bv)
{
    __shared__ unsigned sWB[5 * 16 * 49];    // 15.7 KB, B-frags, pair-along-k, stride 49
    int tid = threadIdx.x;
    for (int i = tid; i < 5 * 16 * 49; i += 256) {
        int t = i / 784, r2 = i % 784, cc = r2 / 49, kp = r2 % 49;
        int col = 16 * t + cc;
        sWB[i] = (kp < 40) ? pack2(W[(2 * kp) * D_ + col], W[(2 * kp + 1) * D_ + col]) : 0u;
    }
    __syncthreads();

    int w = tid >> 6;
    int lane = tid & 63;
    int q = lane >> 4;
    int c = lane & 15;
    int base = (blockIdx.x * 4 + w) * 16;
    int node = porder[base + c];
    int off0 = 4 * q, off1 = 16 + 4 * q, off2 = 32 + 4 * q;

    // ---- edge aggregation into f32 A-slices ----
    float A0[8] = {0.f, 0.f, 0.f, 0.f, 0.f, 0.f, 0.f, 0.f};
    float A1[8] = {0.f, 0.f, 0.f, 0.f, 0.f, 0.f, 0.f, 0.f};
    float A2[8] = {0.f, 0.f, 0.f, 0.f, 0.f, 0.f, 0.f, 0.f};
    uint4 zz = make_uint4(0u, 0u, 0u, 0u);

    int e = start[node];
    int s1 = start[node + 1];
    while (__any(e < s1)) {
        bool a0 = e < s1;
        bool a1 = (e + 1) < s1;
        int ee0 = max(min(e, s1 - 1), 0);
        int ee1 = max(min(e + 1, s1 - 1), 0);
        int2 ed0 = e2[ee0];
        int2 ed1 = e2[ee1];
        uint4 s00, s01, s02, s10, s11, s12;
        if (L == 1) {
            int m0 = mapper[ed0.x];
            int m1 = mapper[ed1.x];
            const unsigned* x0 = xb + (size_t)m0 * 32;
            const unsigned* x1 = xb + (size_t)m1 * 32;
            s00 = *(const uint4*)(x0 + off0);
            s01 = *(const uint4*)(x0 + off1);
            s02 = (q < 2) ? *(const uint4*)(htb + (ed0.y & 31) * 8 + off0) : zz;
            s10 = *(const uint4*)(x1 + off0);
            s11 = *(const uint4*)(x1 + off1);
            s12 = (q < 2) ? *(const uint4*)(htb + (ed1.y & 31) * 8 + off0) : zz;
        } else {
            const unsigned* h0 = hin + (size_t)ed0.x * 40;
            const unsigned* h1 = hin + (size_t)ed1.x * 40;
            s00 = *(const uint4*)(h0 + off0);
            s01 = *(const uint4*)(h0 + off1);
            s02 = (q < 2) ? *(const uint4*)(h0 + off2) : zz;
            s10 = *(const uint4*)(h1 + off0);
            s11 = *(const uint4*)(h1 + off1);
            s12 = (q < 2) ? *(const uint4*)(h1 + off2) : zz;
        }
        int em0 = ed0.y >> 5, em1 = ed1.y >> 5;
        if (EA16) {
            const unsigned* e0p = eab + (size_t)em0 * 40;
            const unsigned* e1p = eab + (size_t)em1 * 40;
            uint4 q00 = *(const uint4*)(e0p + off0);
            uint4 q01 = *(const uint4*)(e0p + off1);
            uint4 q02 = (q < 2) ? *(const uint4*)(e0p + off2) : zz;
            uint4 q10 = *(const uint4*)(e1p + off0);
            uint4 q11 = *(const uint4*)(e1p + off1);
            uint4 q12 = (q < 2) ? *(const uint4*)(e1p + off2) : zz;
            if (a0) { acc4(A0, s00, q00); acc4(A1, s01, q01); if (q < 2) acc4(A2, s02, q02); }
            if (a1) { acc4(A0, s10, q10); acc4(A1, s11, q11); if (q < 2) acc4(A2, s12, q12); }
        } else {
            const float* e0p = eaf + (size_t)em0 * 80;
            const float* e1p = eaf + (size_t)em1 * 80;
            if (a0) { acc4f(A0, s00, e0p, off0); acc4f(A1, s01, e0p, off1); if (q < 2) acc4f(A2, s02, e0p, off2); }
            if (a1) { acc4f(A0, s10, e1p, off0); acc4f(A1, s11, e1p, off1); if (q < 2) acc4f(A2, s12, e1p, off2); }
        }
        e += 2;
    }

    // ---- own h (A-slices) ----
    uint4 h0v, h1v, h2v;
    if (L == 1) {
        int m = mapper[node];
        int hp = hop[node] + 1;
        const unsigned* xr = xb + (size_t)m * 32;
        h0v = *(const uint4*)(xr + off0);
        h1v = *(const uint4*)(xr + off1);
        h2v = (q < 2) ? *(const uint4*)(htb + hp * 8 + off0) : zz;
    } else {
        const unsigned* hr = hin + (size_t)node * 40;
        h0v = *(const uint4*)(hr + off0);
        h1v = *(const uint4*)(hr + off1);
        h2v = (q < 2) ? *(const uint4*)(hr + off2) : zz;
    }

    // ---- A = bf16(h + agg) ----
    FragU a0F, a1F, a2F;
    {
        const unsigned* hp0 = (const unsigned*)&h0v;
        const unsigned* hp1 = (const unsigned*)&h1v;
        const unsigned* hp2 = (const unsigned*)&h2v;
        unsigned r0[4], r1[4], r2[4];
        #pragma unroll
        for (int j = 0; j < 4; j++) {
            float2 f0 = bf2f(hp0[j]);
            float2 f1 = bf2f(hp1[j]);
            float2 f2 = bf2f(hp2[j]);
            r0[j] = pack2(A0[2 * j] + f0.x, A0[2 * j + 1] + f0.y);
            r1[j] = pack2(A1[2 * j] + f1.x, A1[2 * j + 1] + f1.y);
            r2[j] = (q < 2) ? pack2(A2[2 * j] + f2.x, A2[2 * j + 1] + f2.y) : 0u;
        }
        a0F.u = make_uint4(r0[0], r0[1], r0[2], r0[3]);
        a1F.u = make_uint4(r1[0], r1[1], r1[2], r1[3]);
        a2F.u = make_uint4(r2[0], r2[1], r2[2], r2[3]);
    }

    // ---- GEMM: 5 col-tiles x 3 K-steps = 15 MFMA ----
    f32x4 acc[5];
    #pragma unroll
    for (int t = 0; t < 5; t++) {
        const unsigned* pb = sWB + (t * 16 + c) * 49 + 4 * q;
        FragU b0, b1, b2;
        b0.u = *(const uint4*)(pb);
        b1.u = *(const uint4*)(pb + 16);
        b2.u = *(const uint4*)(pb + 32);
        f32x4 z = {0.f, 0.f, 0.f, 0.f};
        acc[t] = __builtin_amdgcn_mfma_f32_16x16x32_bf16(a0F.b, b0.b, z, 0, 0, 0);
        acc[t] = __builtin_amdgcn_mfma_f32_16x16x32_bf16(a1F.b, b1.b, acc[t], 0, 0, 0);
        acc[t] = __builtin_amdgcn_mfma_f32_16x16x32_bf16(a2F.b, b2.b, acc[t], 0, 0, 0);
    }

    // ---- epilogue rows 4q+r: BN + ReLU + residual, pack-store ----
    int prow[4], mm2[4], hp2v[4];
    #pragma unroll
    for (int r = 0; r < 4; r++) {
        prow[r] = porder[base + 4 * q + r];
        if (L == 1) {
            mm2[r] = mapper[prow[r]];
            hp2v[r] = hop[prow[r]] + 1;
        }
    }
    #pragma unroll
    for (int t = 0; t < 5; t++) {
        int col = 16 * t + c;
        float gc_ = gv[col], bc_ = bv[col];
        #pragma unroll
        for (int r = 0; r < 4; r++) {
            unsigned hu;
            if (L == 1) {
                hu = (t < 4) ? xb[(size_t)mm2[r] * 32 + 8 * t + (c >> 1)]
                             : htb[hp2v[r] * 8 + (c >> 1)];
            } else {
                hu = hin[(size_t)prow[r] * 40 + 8 * t + (c >> 1)];
            }
            float2 hf = bf2f(hu);
            float hres = (c & 1) ? hf.y : hf.x;
            float o = fmaxf(gc_ * acc[t][r] + bc_, 0.f) + hres;
            float partner = __shfl_xor(o, 1);
            if (!(c & 1)) outp[(size_t)prow[r] * 40 + 8 * t + (c >> 1)] = pack2(o, partner);
        }
    }
}

// ---------------- MFMA head: oe + gates + sub/ctx; ctx rows written at npos (sorted) ----------------
__global__ __launch_bounds__(256) void k_headm(
    const unsigned* __restrict__ h2u, const int* __restrict__ hop,
    const int* __restrict__ mapper, const int* __restrict__ npos,
    const float* __restrict__ gall,
    const float* __restrict__ oe_w, const float* __restrict__ oe_b,
    const float* __restrict__ sub_w, const float* __restrict__ sub_b,
    const float* __restrict__ sub_g, const float* __restrict__ sub_bt,
    const float* __restrict__ ctx_w, const float* __restrict__ ctx_b,
    const float* __restrict__ ctx_g, const float* __restrict__ ctx_bt,
    float* __restrict__ cent, float* __restrict__ subp, unsigned* __restrict__ ctxv)
{
    __shared__ unsigned sOE[4 * 16 * 48];   // 12 KB
    __shared__ unsigned sSB[4 * 16 * 40];   // 10 KB
    __shared__ unsigned sCX[4 * 16 * 40];   // 10 KB
    __shared__ float    sT[4][16 * 68];     // 17 KB
    int tid = threadIdx.x;
    for (int i = tid; i < 4 * 16 * 48; i += 256) {
        int t = i / (16 * 48), r2 = i % (16 * 48), cc = r2 / 48, kp = r2 % 48;
        int col = 16 * t + cc;
        sOE[i] = (kp < 40) ? pack2(oe_w[(2 * kp) * 64 + col], oe_w[(2 * kp + 1) * 64 + col]) : 0u;
    }
    for (int i = tid; i < 4 * 16 * 40; i += 256) {
        int t = i / (16 * 40), r2 = i % (16 * 40), cc = r2 / 40, kp = r2 % 40;
        int col = 16 * t + cc;
        bool ok = kp < 32;
        sSB[i] = ok ? pack2(sub_w[(2 * kp) * 64 + col], sub_w[(2 * kp + 1) * 64 + col]) : 0u;
        sCX[i] = ok ? pack2(ctx_w[(2 * kp) * 64 + col], ctx_w[(2 * kp + 1) * 64 + col]) : 0u;
    }
    __syncthreads();

    int w = tid >> 6;
    int lane = tid & 63;
    int q = lane >> 4;
    int c = lane & 15;
    int base = (blockIdx.x * 4 + w) * 16;

    const uint4* hrow = (const uint4*)(h2u + (size_t)(base + c) * 40);
    FragU a0, a1, a2;
    a0.u = hrow[q];
    a1.u = hrow[4 + q];
    a2.u = make_uint4(0u, 0u, 0u, 0u);
    if (q < 2) a2.u = hrow[8 + q];

    f32x4 acc[4];
    #pragma unroll
    for (int t = 0; t < 4; t++) {
        const unsigned* pb = sOE + (t * 16 + c) * 48 + 4 * q;
        FragU b0, b1, b2;
        b0.u = *(const uint4*)(pb);
        b1.u = *(const uint4*)(pb + 16);
        b2.u = *(const uint4*)(pb + 32);
        f32x4 z = {0.f, 0.f, 0.f, 0.f};
        acc[t] = __builtin_amdgcn_mfma_f32_16x16x32_bf16(a0.b, b0.b, z, 0, 0, 0);
        acc[t] = __builtin_amdgcn_mfma_f32_16x16x32_bf16(a1.b, b1.b, acc[t], 0, 0, 0);
        acc[t] = __builtin_amdgcn_mfma_f32_16x16x32_bf16(a2.b, b2.b, acc[t], 0, 0, 0);
    }

    int mm[4], hn[4], np[4];
    #pragma unroll
    for (int r = 0; r < 4; r++) {
        int node = base + 4 * q + r;
        mm[r] = mapper[node];
        hn[r] = hop[node] + 1;
        np[r] = npos[node];
    }
    int sgA = base / S_;
    int k0 = (sgA + 1) * S_ - base;
    if (k0 > 16) k0 = 16;

    #pragma unroll
    for (int t = 0; t < 4; t++) {
        int col = 16 * t + c;
        float ob = oe_b[col];
        #pragma unroll
        for (int r = 0; r < 4; r++) {
            int row = 4 * q + r;
            float v = acc[t][r] + ob;
            sT[w][row * 68 + col] = v;
            int sg = (row < k0) ? sgA : sgA + 1;
            if (mm[r] == sg) {
                cent[(size_t)sg * 64 + col] = v * gall[hn[r] * 64 + col];
            }
        }
    }

    const float* trp = &sT[w][c * 68 + 8 * q];
    float4 v0 = *(const float4*)(trp);
    float4 v1 = *(const float4*)(trp + 4);
    float4 v2 = *(const float4*)(trp + 32);
    float4 v3 = *(const float4*)(trp + 36);
    FragU ap0, ap1;
    ap0.u = make_uint4(pack2(v0.x, v0.y), pack2(v0.z, v0.w), pack2(v1.x, v1.y), pack2(v1.z, v1.w));
    ap1.u = make_uint4(pack2(v2.x, v2.y), pack2(v2.z, v2.w), pack2(v3.x, v3.y), pack2(v3.z, v3.w));

    f32x4 sa[4], ca[4];
    #pragma unroll
    for (int t = 0; t < 4; t++) {
        const unsigned* ps = sSB + (t * 16 + c) * 40 + 4 * q;
        const unsigned* pc = sCX + (t * 16 + c) * 40 + 4 * q;
        FragU b0, b1, d0, d1;
        b0.u = *(const uint4*)(ps);
        b1.u = *(const uint4*)(ps + 16);
        d0.u = *(const uint4*)(pc);
        d1.u = *(const uint4*)(pc + 16);
        f32x4 z = {0.f, 0.f, 0.f, 0.f};
        sa[t] = __builtin_amdgcn_mfma_f32_16x16x32_bf16(ap0.b, b0.b, z, 0, 0, 0);
        sa[t] = __builtin_amdgcn_mfma_f32_16x16x32_bf16(ap1.b, b1.b, sa[t], 0, 0, 0);
        ca[t] = __builtin_amdgcn_mfma_f32_16x16x32_bf16(ap0.b, d0.b, z, 0, 0, 0);
        ca[t] = __builtin_amdgcn_mfma_f32_16x16x32_bf16(ap1.b, d1.b, ca[t], 0, 0, 0);
    }

    #pragma unroll
    for (int t = 0; t < 4; t++) {
        int col = 16 * t + c;
        float sb = sub_b[col], sgm = sub_g[col], sbt = sub_bt[col];
        float cb = ctx_b[col], cgm = ctx_g[col], cbt = ctx_bt[col];
        float sA = 0.f, sB = 0.f;
        #pragma unroll
        for (int r = 0; r < 4; r++) {
            int row = 4 * q + r;
            float sval = fmaxf(sgm * (sa[t][r] + sb) + sbt, 0.f) * gall[(20 + hn[r]) * 64 + col];
            float cval = fmaxf(cgm * (ca[t][r] + cb) + cbt, 0.f) * gall[(40 + hn[r]) * 64 + col];
            float partner = __shfl_xor(cval, 1);
            if ((c & 1) == 0) {
                ctxv[(size_t)np[r] * 32 + (col >> 1)] = pack2(cval, partner);
            }
            if (row < k0) sA += sval; else sB += sval;
        }
        sA += __shfl_xor(sA, 16); sA += __shfl_xor(sA, 32);
        sB += __shfl_xor(sB, 16); sB += __shfl_xor(sB, 32);
        if (q == 0) {
            atomicAdd(&subp[(size_t)sgA * 64 + col], sA);
            if (k0 < 16) atomicAdd(&subp[(size_t)(sgA + 1) * 64 + col], sB);
        }
    }
}

// ---------------- ctx pool: ctxv rows are in mapper-sorted order -> pure streaming ----------------
__global__ __launch_bounds__(256) void k_ctxpool(
    const unsigned* __restrict__ ctxv, const int* __restrict__ nstart,
    float* __restrict__ ctxp)
{
    int w = threadIdx.x >> 6, d = threadIdx.x & 63;
    int n = blockIdx.x * 4 + w;
    if (n >= N_) return;
    int s0 = nstart[n], s1 = nstart[n + 1];
    int dh = d >> 1;
    float acc = 0.f;
    int i = s0;
    for (; i + 4 <= s1; i += 4) {
        float2 f0 = bf2f(ctxv[(size_t)i * 32 + dh]);
        float2 f1 = bf2f(ctxv[(size_t)(i + 1) * 32 + dh]);
        float2 f2 = bf2f(ctxv[(size_t)(i + 2) * 32 + dh]);
        float2 f3 = bf2f(ctxv[(size_t)(i + 3) * 32 + dh]);
        acc += (d & 1) ? (f0.y + f1.y + f2.y + f3.y) : (f0.x + f1.x + f2.x + f3.x);
    }
    for (; i < s1; i++) {
        float2 f = bf2f(ctxv[(size_t)i * 32 + dh]);
        acc += (d & 1) ? f.y : f.x;
    }
    ctxp[(size_t)n * 64 + d] = acc;
}

// ---------------- final: combine pools + out_encoder ----------------
__global__ __launch_bounds__(256) void k_final(
    const float* __restrict__ cent, const float* __restrict__ subp, const float* __restrict__ ctxp,
    const int* __restrict__ nstart,
    const float* __restrict__ fo_w, const float* __restrict__ fo_b,
    const float* __restrict__ fo_g, const float* __restrict__ fo_bt,
    float* __restrict__ out)
{
    __shared__ float sW[64 * 64];
    int tid = threadIdx.x;
    for (int i = tid; i < 4096; i += 256) sW[i] = fo_w[i];
    int d = tid & 63, grp = tid >> 6;
    float rb = fo_b[d], rg = fo_g[d], rbt = fo_bt[d];
    __syncthreads();
    for (int n = blockIdx.x * 4 + grp; n < N_; n += gridDim.x * 4) {
        float cm = (float)max(nstart[n + 1] - nstart[n], 1);
        size_t o = (size_t)n * 64 + d;
        float r = cent[o] + subp[o] * (1.f / 20.f) + ctxp[o] / cm;
        float dot = rb;
        #pragma unroll 8
        for (int k = 0; k < 64; k++) dot += __shfl(r, k) * sW[k * 64 + d];
        out[o] = rg * dot + rbt;
    }
}

// ---------------- launch ----------------
extern "C" void kernel_launch(void* const* d_in, const int* in_sizes, int n_in,
                              void* d_out, int out_size, void* d_ws, size_t ws_size,
                              hipStream_t stream) {
    const float* x         = (const float*)d_in[0];
    const float* edge_attr = (const float*)d_in[1];
    const float* hop_table = (const float*)d_in[2];
    const float* conv_w1   = (const float*)d_in[3];
    const float* bn1_g     = (const float*)d_in[4];
    const float* bn1_b     = (const float*)d_in[5];
    const float* conv_w2   = (const float*)d_in[6];
    const float* bn2_g     = (const float*)d_in[7];
    const float* bn2_b     = (const float*)d_in[8];
    const float* oe_w      = (const float*)d_in[9];
    const float* oe_b      = (const float*)d_in[10];
    const float* sub_w     = (const float*)d_in[11];
    const float* sub_b     = (const float*)d_in[12];
    const float* sub_g     = (const float*)d_in[13];
    const float* sub_bt    = (const float*)d_in[14];
    const float* ctx_w     = (const float*)d_in[15];
    const float* ctx_b     = (const float*)d_in[16];
    const float* ctx_g     = (const float*)d_in[17];
    const float* ctx_bt    = (const float*)d_in[18];
    const float* gc_w      = (const float*)d_in[19];
    const float* gc_b      = (const float*)d_in[20];
    const float* gs_w      = (const float*)d_in[21];
    const float* gs_b      = (const float*)d_in[22];
    const float* gx_w      = (const float*)d_in[23];
    const float* gx_b      = (const float*)d_in[24];
    const float* fo_w      = (const float*)d_in[25];
    const float* fo_b      = (const float*)d_in[26];
    const float* fo_g      = (const float*)d_in[27];
    const float* fo_bt     = (const float*)d_in[28];
    const int* nodes_mapper  = (const int*)d_in[29];
    const int* edges_mapper  = (const int*)d_in[30];
    const int* edge_index    = (const int*)d_in[31];
    const int* batch         = (const int*)d_in[32];
    const int* hop_indicator = (const int*)d_in[33];
    (void)batch;
    float* out = (float*)d_out;

    size_t off = 0;
    auto alloc = [&](size_t bytes) -> char* {
        char* p = (char*)d_ws + off;
        off = (off + bytes + 255) & ~(size_t)255;
        return p;
    };
    unsigned* hbuf0 = (unsigned*)alloc((size_t)NC_ * 40 * 4);  // 64 MB: h2
    unsigned* hbuf1 = (unsigned*)alloc((size_t)NC_ * 40 * 4);  // 64 MB: h1 -> ctxv
    int*   start    = (int*)alloc((size_t)(NC_ + 1) * 4);
    int*   cursor   = (int*)alloc((size_t)NC_ * 4);
    int*   bsums    = (int*)alloc(2048 * 4);
    int2*  e2       = (int2*)alloc((size_t)EC_ * 8);           // 16 MB
    float* cent     = (float*)alloc((size_t)N_ * 64 * 4);
    float* subp     = (float*)alloc((size_t)N_ * 64 * 4);
    float* ctxp     = (float*)alloc((size_t)N_ * 64 * 4);
    int*   nstart   = (int*)alloc((size_t)(N_ + 1) * 4);
    int*   cursor_n = (int*)alloc((size_t)N_ * 4);
    int*   bsums_n  = (int*)alloc(256 * 4);
    int*   nidx     = (int*)alloc((size_t)NC_ * 4);
    int*   npos     = (int*)alloc((size_t)NC_ * 4);            // 1.6 MB (inverse of nidx)
    float* gall     = (float*)alloc((size_t)60 * 64 * 4);
    unsigned* xb    = (unsigned*)alloc((size_t)N_ * 32 * 4);   // 2.56 MB
    unsigned* htb   = (unsigned*)alloc((size_t)20 * 8 * 4);
    int*   hist     = (int*)alloc((size_t)(DBIN_ * NB_ + 1) * 4);  // 400 KB
    int*   bsums_h  = (int*)alloc(512 * 4);
    int*   porder   = (int*)alloc((size_t)NC_ * 4);            // 1.6 MB
    size_t ea16_bytes = (size_t)EB_ * 40 * 4;                  // 32 MB
    bool use_ea16 = (off + ea16_bytes + 256) <= ws_size;
    unsigned* eab = use_ea16 ? (unsigned*)alloc(ea16_bytes) : nullptr;
    unsigned* ctxv = hbuf1;
    (void)in_sizes; (void)n_in; (void)out_size;

    hipMemsetAsync(cursor, 0, (size_t)NC_ * 4, stream);
    hipMemsetAsync(cursor_n, 0, (size_t)N_ * 4, stream);
    hipMemsetAsync(subp, 0, (size_t)N_ * 64 * 4, stream);

    // fused preprocessing (ea16 + xb + htb + gates)
    {
        int total = EB_ * 40 + N_ * 32 + 160 + 1280;
        k_prep<<<(total + 255) / 256, 256, 0, stream>>>(eab, edge_attr, xb, x, htb, hop_table,
                                                        gall, gc_w, gc_b, gs_w, gs_b, gx_w, gx_b);
    }

    // counts (edge degree + mapper histogram), then the two scans
    k_cnt<<<(EC_ + 255) / 256, 256, 0, stream>>>(edge_index, cursor, nodes_mapper, cursor_n);
    k_bsum<<<NB_, 256, 0, stream>>>(cursor, bsums, NC_);
    k_scan_bsums<<<1, 256, 0, stream>>>(bsums, NB_);
    k_scan_apply<<<NB_, 256, 0, stream>>>(cursor, start, bsums, NC_, EC_);
    k_bsum<<<NBN_, 256, 0, stream>>>(cursor_n, bsums_n, N_);
    k_scan_bsums<<<1, 256, 0, stream>>>(bsums_n, NBN_);
    k_scan_apply<<<NBN_, 256, 0, stream>>>(cursor_n, nstart, bsums_n, N_, NC_);

    // fills (e2 + nidx + npos)
    k_fillall<<<(EC_ + 255) / 256, 256, 0, stream>>>(edge_index, edges_mapper, hop_indicator,
                                                     cursor, e2, nodes_mapper, cursor_n,
                                                     nidx, npos);

    // degree-balanced node order (descending degree; atomic-free counting sort)
    k_lhist<<<NB_, 256, 0, stream>>>(start, hist);
    k_bsum<<<NHB_, 256, 0, stream>>>(hist, bsums_h, DBIN_ * NB_);
    k_scan_bsums<<<1, 256, 0, stream>>>(bsums_h, NHB_);
    k_scan_apply<<<NHB_, 256, 0, stream>>>(hist, hist, bsums_h, DBIN_ * NB_, NC_);
    k_dscatter2<<<NB_, 256, 0, stream>>>(start, hist, porder);

    // fused layers (degree-balanced waves, heavy-first dispatch)
    if (use_ea16) {
        k_gine_f<1, true><<<NC_ / 64, 256, 0, stream>>>(nullptr, xb, htb, nodes_mapper,
                                                        hop_indicator, eab, edge_attr,
                                                        start, e2, porder, hbuf1,
                                                        conv_w1, bn1_g, bn1_b);
        k_gine_f<2, true><<<NC_ / 64, 256, 0, stream>>>(hbuf1, xb, htb, nodes_mapper,
                                                        hop_indicator, eab, edge_attr,
                                                        start, e2, porder, hbuf0,
                                                        conv_w2, bn2_g, bn2_b);
    } else {
        k_gine_f<1, false><<<NC_ / 64, 256, 0, stream>>>(nullptr, xb, htb, nodes_mapper,
                                                         hop_indicator, eab, edge_attr,
                                                         start, e2, porder, hbuf1,
                                                         conv_w1, bn1_g, bn1_b);
        k_gine_f<2, false><<<NC_ / 64, 256, 0, stream>>>(hbuf1, xb, htb, nodes_mapper,
                                                         hop_indicator, eab, edge_attr,
                                                         start, e2, porder, hbuf0,
                                                         conv_w2, bn2_g, bn2_b);
    }

    // MFMA head (h2 = hbuf0; ctxv aliases hbuf1, rows written at npos -> sorted order)
    k_headm<<<NC_ / 64, 256, 0, stream>>>(hbuf0, hop_indicator, nodes_mapper, npos, gall,
                                          oe_w, oe_b, sub_w, sub_b, sub_g, sub_bt,
                                          ctx_w, ctx_b, ctx_g, ctx_bt,
                                          cent, subp, ctxv);

    // ctx pool: pure streaming over sorted ctxv
    k_ctxpool<<<N_ / 4, 256, 0, stream>>>(ctxv, nstart, ctxp);

    // final combine + out encoder
    k_final<<<1280, 256, 0, stream>>>(cent, subp, ctxp, nstart, fo_w, fo_b, fo_g, fo_bt, out);
}